// Round 2
// baseline (937.337 us; speedup 1.0000x reference)
//
#include <hip/hip_runtime.h>

typedef __attribute__((ext_vector_type(8))) short bf16x8;
typedef __attribute__((ext_vector_type(8))) unsigned short u16x8;
typedef __attribute__((ext_vector_type(4))) unsigned short u16x4;
typedef __attribute__((ext_vector_type(4))) float f32x4;

#define DEV static __device__ __forceinline__

DEV unsigned short f2bf(float f){
  unsigned u = __float_as_uint(f);
  u += 0x7fff + ((u>>16)&1);
  return (unsigned short)(u>>16);
}
DEV float bf2f(unsigned short b){ return __uint_as_float(((unsigned)b)<<16); }

DEV void gll16(const void* g, void* l){
  __builtin_amdgcn_global_load_lds((__attribute__((address_space(1))) unsigned*)(void*)g,
                                   (__attribute__((address_space(3))) unsigned*)l, 16, 0, 0);
}

// ---------------- cast fp32 -> bf16 (vectorized) ----------------
__global__ void k_cast(const float* __restrict__ x, unsigned short* __restrict__ y, int n4){
  int i = blockIdx.x*256 + threadIdx.x;
  if (i >= n4) return;
  f32x4 v = ((const f32x4*)x)[i];
  u16x4 o = { f2bf(v.x), f2bf(v.y), f2bf(v.z), f2bf(v.w) };
  ((u16x4*)y)[i] = o;
}

// ---------------- bf16 GEMM: Y = X @ W^T (+bias), m97-style 128x128 tile ----------------
// X rows remapped: xrow = (R>>tpb_log2)*stot + soff + (R & (tpb-1)) + local
__global__ __launch_bounds__(256) void k_gemm(
    const unsigned short* __restrict__ X, const unsigned short* __restrict__ W,
    unsigned short* __restrict__ Yb, float* __restrict__ Yf,
    const float* __restrict__ bias,
    int N, int K, int tpb_log2, int stot, int soff)
{
  __shared__ unsigned short As[2][4096];
  __shared__ unsigned short Bs[2][4096];
  const int t = threadIdx.x, w = t>>6, l = t&63;
  const int R = blockIdx.x*128, C = blockIdx.y*128;
  const long xbase = (long)(R>>tpb_log2)*stot + soff + (R & ((1<<tpb_log2)-1));
  const int wr = w>>1, wc = w&1;
  f32x4 acc[4][4] = {};
  const int nk = K>>5;

  auto stage = [&](int buf, int kt){
    const int k0 = kt*32;
    #pragma unroll
    for (int c=0;c<2;c++){
      int row = c*64 + (t>>2);
      int scol = ((t&3)<<3) ^ ((row&3)<<3);           // 4-way XOR pre-swizzle of source
      gll16(X + (xbase+row)*K + k0 + scol, &As[buf][c*2048 + w*512]);
      gll16(W + (long)(C+row)*K + k0 + scol, &Bs[buf][c*2048 + w*512]);
    }
  };

  stage(0,0);
  int buf = 0;
  for (int kt=0; kt<nk; kt++){
    __syncthreads();                       // drains vmcnt for staging + lgkm for prior reads
    if (kt+1 < nk) stage(buf^1, kt+1);
    bf16x8 a[4], b[4];
    #pragma unroll
    for (int m=0;m<4;m++){
      int ar = wr*64 + m*16 + (l&15);
      int ac = ((l>>4)<<3) ^ ((ar&3)<<3);
      a[m] = *(const bf16x8*)&As[buf][ar*32 + ac];
      int br = wc*64 + m*16 + (l&15);
      int bc = ((l>>4)<<3) ^ ((br&3)<<3);
      b[m] = *(const bf16x8*)&Bs[buf][br*32 + bc];
    }
    #pragma unroll
    for (int m=0;m<4;m++)
      #pragma unroll
      for (int n=0;n<4;n++)
        acc[m][n] = __builtin_amdgcn_mfma_f32_16x16x32_bf16(a[m], b[n], acc[m][n], 0,0,0);
    buf ^= 1;
  }

  #pragma unroll
  for (int m=0;m<4;m++){
    int row = R + wr*64 + m*16 + ((l>>4)<<2);
    #pragma unroll
    for (int n=0;n<4;n++){
      int col = C + wc*64 + n*16 + (l&15);
      float bvv = bias ? bias[col] : 0.0f;
      #pragma unroll
      for (int r=0;r<4;r++){
        float v = acc[m][n][r] + bvv;
        long idx = (long)(row+r)*N + col;
        if (Yf) Yf[idx] = v;
        else Yb[idx] = f2bf(v);
      }
    }
  }
}

// ---------------- fused RMSNorm + RoPE postprocess (one wave per (token,head)) ----------------
__global__ void k_ppqk(const unsigned short* __restrict__ Y, const float* __restrict__ nw,
    const float* __restrict__ cs, const float* __restrict__ sn, unsigned short* __restrict__ dst,
    int T_log2, int tpb_log2, int dest_off, int S, int no_batch,
    int pos_off, int pos_mask, float qscale)
{
  int rid = blockIdx.x*4 + (threadIdx.x>>6);
  int l = threadIdx.x & 63;
  int h = rid >> T_log2, tk = rid & ((1<<T_log2)-1);
  unsigned pair = *(const unsigned*)(Y + (long)tk*3072 + h*128 + 2*l);
  float x0 = bf2f((unsigned short)(pair&0xffff));
  float x1 = bf2f((unsigned short)(pair>>16));
  float ss = x0*x0 + x1*x1;
  #pragma unroll
  for (int m=1;m<64;m<<=1) ss += __shfl_xor(ss, m);
  float rr = rsqrtf(ss*(1.0f/128.0f) + 1e-6f);
  x0 *= rr*nw[2*l]; x1 *= rr*nw[2*l+1];
  int p = pos_off + (tk & pos_mask);
  float c0 = cs[p*128 + 2*l], c1 = cs[p*128 + 2*l+1];
  float s0 = sn[p*128 + 2*l], s1 = sn[p*128 + 2*l+1];
  float o0 = (x0*c0 - x1*s0)*qscale;
  float o1 = (x1*c1 + x0*s1)*qscale;
  long idx;
  if (no_batch) idx = (long)h*S + tk;
  else {
    int b = tk >> tpb_log2;
    int sq = dest_off + (tk & ((1<<tpb_log2)-1));
    idx = (long)(b*24+h)*S + sq;
  }
  unsigned out = (unsigned)f2bf(o0) | ((unsigned)f2bf(o1)<<16);
  *(unsigned*)(dst + idx*128 + 2*l) = out;
}

// ---------------- V reorder + transpose: Vt[(b,)h][d][j] ----------------
__global__ void k_ppv(const unsigned short* __restrict__ Y, unsigned short* __restrict__ Vt,
                      int vstr, int no_batch)
{
  __shared__ unsigned short tileS[64][136];
  int t = threadIdx.x, h = blockIdx.y;
  int tile0 = blockIdx.x*64;
  #pragma unroll
  for (int c=0;c<4;c++){
    int j = c*16 + (t>>4), col = (t&15)*8;
    *(u16x8*)&tileS[j][col] = *(const u16x8*)(Y + (long)(tile0+j)*3072 + h*128 + col);
  }
  __syncthreads();
  int d = t>>1, half = t&1;
  unsigned short tmp[32];
  #pragma unroll
  for (int i=0;i<32;i++) tmp[i] = tileS[half*32+i][d];
  long base;
  if (no_batch) base = ((long)h*128 + d)*vstr + tile0 + half*32;
  else { int b = tile0>>9; base = ((long)(b*24+h)*128 + d)*vstr + (tile0&511) + half*32; }
  #pragma unroll
  for (int k=0;k<4;k++) *(u16x8*)(Vt + base + k*8) = *(const u16x8*)&tmp[k*8];
}

// ---------------- flash attention: 64 Q-rows/block, KV tiles of 64 ----------------
__global__ __launch_bounds__(256) void k_attn(
    const unsigned short* __restrict__ Q,
    const unsigned short* __restrict__ Ke, const unsigned short* __restrict__ Ki,
    const unsigned short* __restrict__ Ve, const unsigned short* __restrict__ Vi,
    unsigned short* __restrict__ AO)
{
  __shared__ unsigned short Ks[8192];          // [64 kv][128 d], XOR-swizzled
  __shared__ unsigned short Vs[8192];          // [128 d][64 kv], XOR-swizzled
  __shared__ unsigned short Ps[4][1408];       // per-wave P tile [16][88]
  const int t = threadIdx.x, w = t>>6, l = t&63;
  const int h = blockIdx.y, b = blockIdx.z;
  const int bh = b*24 + h;
  const int q0 = blockIdx.x*64 + w*16;

  bf16x8 qf[4];
  {
    const unsigned short* qp = Q + ((long)bh*1536 + q0 + (l&15))*128 + ((l>>4)<<3);
    #pragma unroll
    for (int kc=0;kc<4;kc++) qf[kc] = *(const bf16x8*)(qp + kc*32);
  }
  f32x4 o[8] = {};
  float mx[4] = {-1e30f,-1e30f,-1e30f,-1e30f};
  float ls[4] = {0,0,0,0};

  for (int jt=0; jt<40; jt++){
    const unsigned short *ksrc, *vsrc; int vstr;
    if (jt < 8){
      ksrc = Ke + ((long)bh*512 + jt*64)*128;
      vsrc = Ve + (long)bh*65536 + jt*64;
      vstr = 512;
    } else {
      ksrc = Ki + ((long)h*2048 + (jt-8)*64)*128;
      vsrc = Vi + (long)h*262144 + (jt-8)*64;
      vstr = 2048;
    }
    #pragma unroll
    for (int c=0;c<4;c++){
      int row = c*16 + (t>>4);
      int col = ((t&15)<<3) ^ ((row&7)<<3);
      gll16(ksrc + row*128 + col, &Ks[c*2048 + w*512]);
    }
    #pragma unroll
    for (int c=0;c<4;c++){
      int row = c*32 + (t>>3);
      int col = ((t&7)<<3) ^ ((row&7)<<3);
      gll16(vsrc + (long)row*vstr + col, &Vs[c*2048 + w*512]);
    }
    __syncthreads();

    f32x4 sf[4];
    #pragma unroll
    for (int ct=0;ct<4;ct++){
      f32x4 s = {};
      #pragma unroll
      for (int kc=0;kc<4;kc++){
        int krow = ct*16 + (l&15);
        int kcol = (kc*32 + ((l>>4)<<3)) ^ ((krow&7)<<3);
        bf16x8 kb = *(const bf16x8*)&Ks[krow*128 + kcol];
        s = __builtin_amdgcn_mfma_f32_16x16x32_bf16(qf[kc], kb, s, 0,0,0);
      }
      sf[ct] = s;
    }

    float al[4], rsum[4];
    #pragma unroll
    for (int r=0;r<4;r++){
      float pm = fmaxf(fmaxf(sf[0][r],sf[1][r]), fmaxf(sf[2][r],sf[3][r]));
      #pragma unroll
      for (int m=1;m<16;m<<=1) pm = fmaxf(pm, __shfl_xor(pm, m));
      float mn = fmaxf(mx[r], pm);
      al[r] = exp2f(mx[r]-mn);
      mx[r] = mn;
      rsum[r] = 0.f;
    }
    #pragma unroll
    for (int ct=0;ct<4;ct++){
      #pragma unroll
      for (int r=0;r<4;r++){
        float pv = exp2f(sf[ct][r]-mx[r]);
        rsum[r] += pv;
        int prow = ((l>>4)<<2) + r;
        Ps[w][prow*88 + ct*16 + (l&15)] = f2bf(pv);
      }
    }
    #pragma unroll
    for (int r=0;r<4;r++){
      #pragma unroll
      for (int m=1;m<16;m<<=1) rsum[r] += __shfl_xor(rsum[r], m);
      ls[r] = ls[r]*al[r] + rsum[r];
    }
    #pragma unroll
    for (int f=0;f<8;f++){
      #pragma unroll
      for (int r=0;r<4;r++) o[f][r] *= al[r];
    }
    bf16x8 pa[2];
    #pragma unroll
    for (int kc=0;kc<2;kc++)
      pa[kc] = *(const bf16x8*)&Ps[w][(l&15)*88 + kc*32 + ((l>>4)<<3)];
    #pragma unroll
    for (int f=0;f<8;f++){
      #pragma unroll
      for (int kc=0;kc<2;kc++){
        int vrow = f*16 + (l&15);
        int vcol = (kc*32 + ((l>>4)<<3)) ^ ((vrow&7)<<3);
        bf16x8 vb = *(const bf16x8*)&Vs[vrow*64 + vcol];
        o[f] = __builtin_amdgcn_mfma_f32_16x16x32_bf16(pa[kc], vb, o[f], 0,0,0);
      }
    }
    __syncthreads();
  }

  #pragma unroll
  for (int r=0;r<4;r++){
    int qrow = q0 + ((l>>4)<<2) + r;
    float inv = 1.0f/ls[r];
    #pragma unroll
    for (int f=0;f<8;f++){
      AO[((long)b*1536 + qrow)*3072 + h*128 + f*16 + (l&15)] = f2bf(o[f][r]*inv);
    }
  }
}

// ---------------- host launch ----------------
extern "C" void kernel_launch(void* const* d_in, const int* in_sizes, int n_in,
                              void* d_out, int out_size, void* d_ws, size_t ws_size,
                              hipStream_t stream)
{
  const float* hs  = (const float*)d_in[0];
  const float* ehs = (const float*)d_in[1];
  const float* rc  = (const float*)d_in[2];
  const float* rs_ = (const float*)d_in[3];
  const float* wq = (const float*)d_in[4];  const float* bq = (const float*)d_in[5];
  const float* wk = (const float*)d_in[6];  const float* bk = (const float*)d_in[7];
  const float* wv = (const float*)d_in[8];  const float* bv = (const float*)d_in[9];
  const float* waq= (const float*)d_in[10]; const float* baq= (const float*)d_in[11];
  const float* wak= (const float*)d_in[12]; const float* bak= (const float*)d_in[13];
  const float* wav= (const float*)d_in[14]; const float* bav= (const float*)d_in[15];
  const float* wo = (const float*)d_in[16]; const float* bo = (const float*)d_in[17];
  const float* wao= (const float*)d_in[18]; const float* bao= (const float*)d_in[19];
  const float* nq = (const float*)d_in[20]; const float* nk = (const float*)d_in[21];
  const float* naq= (const float*)d_in[22]; const float* nak= (const float*)d_in[23];

  // Workspace layout (107 MB total). AO aliases Xh+Xe (dead after encoder
  // projections complete; k_attn writes AO strictly after those GEMMs).
  char* p = (char*)d_ws;
  auto alloc = [&](size_t bytes){ char* r = p; p += bytes; return r; };
  unsigned short* Xh = (unsigned short*)alloc(12582912);  // hidden bf16 [2048][3072]
  unsigned short* Xe = (unsigned short*)alloc(6291456);   // encoder bf16 [1024][3072]
  unsigned short* Wb = (unsigned short*)alloc(18874368);  // reusable weight bf16 [3072][3072]
  unsigned short* Yb = (unsigned short*)alloc(12582912);  // reusable proj out bf16
  unsigned short* Qb = (unsigned short*)alloc(18874368);  // Q [2][24][1536][128]
  unsigned short* Ke = (unsigned short*)alloc(6291456);   // Kenc [2][24][512][128]
  unsigned short* Ki = (unsigned short*)alloc(12582912);  // Kimg [24][2048][128]
  unsigned short* Ve = (unsigned short*)alloc(6291456);   // Vtenc [2][24][128][512]
  unsigned short* Vi = (unsigned short*)alloc(12582912);  // Vtimg [24][128][2048]
  unsigned short* AO = Xh;                                // attn out bf16 [2][1536][3072] (aliases Xh+Xe)

  const float qsc = (float)(0.08838834764831845 * 1.4426950408889634); // scale * log2(e)

  k_cast<<<6144,256,0,stream>>>(hs, Xh, 1572864);
  k_cast<<<3072,256,0,stream>>>(ehs, Xe, 786432);

  auto cW = [&](const float* ww){ k_cast<<<9216,256,0,stream>>>(ww, Wb, 2359296); };

  // image q/k/v
  cW(wq);
  k_gemm<<<dim3(16,24),256,0,stream>>>(Xh, Wb, Yb, nullptr, bq, 3072,3072, 20,0,0);
  k_ppqk<<<12288,256,0,stream>>>(Yb, nq, rc, rs_, Qb, 11, 10, 512, 1536, 0, 512, 1023, qsc);
  cW(wk);
  k_gemm<<<dim3(16,24),256,0,stream>>>(Xh, Wb, Yb, nullptr, bk, 3072,3072, 20,0,0);
  k_ppqk<<<12288,256,0,stream>>>(Yb, nk, rc, rs_, Ki, 11, 0, 0, 2048, 1, 512, 1023, 1.0f);
  cW(wv);
  k_gemm<<<dim3(16,24),256,0,stream>>>(Xh, Wb, Yb, nullptr, bv, 3072,3072, 20,0,0);
  k_ppv<<<dim3(32,24),256,0,stream>>>(Yb, Vi, 2048, 1);

  // encoder q/k/v
  cW(waq);
  k_gemm<<<dim3(8,24),256,0,stream>>>(Xe, Wb, Yb, nullptr, baq, 3072,3072, 20,0,0);
  k_ppqk<<<6144,256,0,stream>>>(Yb, naq, rc, rs_, Qb, 10, 9, 0, 1536, 0, 0, 511, qsc);
  cW(wak);
  k_gemm<<<dim3(8,24),256,0,stream>>>(Xe, Wb, Yb, nullptr, bak, 3072,3072, 20,0,0);
  k_ppqk<<<6144,256,0,stream>>>(Yb, nak, rc, rs_, Ke, 10, 9, 0, 512, 0, 0, 511, 1.0f);
  cW(wav);
  k_gemm<<<dim3(8,24),256,0,stream>>>(Xe, Wb, Yb, nullptr, bav, 3072,3072, 20,0,0);
  k_ppv<<<dim3(16,24),256,0,stream>>>(Yb, Ve, 512, 0);

  // attention (AO aliases Xh/Xe — both dead by this point)
  k_attn<<<dim3(24,24,2),256,0,stream>>>(Qb, Ke, Ki, Ve, Vi, AO);

  // output projections straight into d_out (fp32)
  cW(wo);
  k_gemm<<<dim3(16,24),256,0,stream>>>(AO, Wb, nullptr, (float*)d_out, bo, 3072,3072, 10, 1536, 512);
  cW(wao);
  k_gemm<<<dim3(8,24),256,0,stream>>>(AO, Wb, nullptr, (float*)d_out + 6291456, bao, 3072,3072, 9, 1536, 0);
}

// Round 3
// 710.821 us; speedup vs baseline: 1.3187x; 1.3187x over previous
//
#include <hip/hip_runtime.h>

typedef __attribute__((ext_vector_type(8))) short bf16x8;
typedef __attribute__((ext_vector_type(8))) unsigned short u16x8;
typedef __attribute__((ext_vector_type(4))) unsigned short u16x4;
typedef __attribute__((ext_vector_type(4))) float f32x4;

#define DEV static __device__ __forceinline__

DEV unsigned short f2bf(float f){
  unsigned u = __float_as_uint(f);
  u += 0x7fff + ((u>>16)&1);
  return (unsigned short)(u>>16);
}
DEV float bf2f(unsigned short b){ return __uint_as_float(((unsigned)b)<<16); }

DEV void gll16(const void* g, void* l){
  __builtin_amdgcn_global_load_lds((__attribute__((address_space(1))) unsigned*)(void*)g,
                                   (__attribute__((address_space(3))) unsigned*)l, 16, 0, 0);
}

// ---------------- cast fp32 -> bf16 (vectorized) ----------------
__global__ void k_cast(const float* __restrict__ x, unsigned short* __restrict__ y, int n4){
  int i = blockIdx.x*256 + threadIdx.x;
  if (i >= n4) return;
  f32x4 v = ((const f32x4*)x)[i];
  u16x4 o = { f2bf(v.x), f2bf(v.y), f2bf(v.z), f2bf(v.w) };
  ((u16x4*)y)[i] = o;
}

// ---------------- bf16 GEMM: Y = X @ W^T (+bias), 128x128 tile, N-fused ----------------
// W is split into sections of sec_nb col-blocks; section s uses W rows
// [s*sec_nb*128, ...) and bias (ba,bb,bc)[s]. X rows remapped via (tpb_log2,stot,soff).
__global__ __launch_bounds__(256) void k_gemm(
    const unsigned short* __restrict__ X, const unsigned short* __restrict__ W,
    unsigned short* __restrict__ Yb, float* __restrict__ Yf,
    const float* __restrict__ ba, const float* __restrict__ bb, const float* __restrict__ bc,
    int N, int K, int sec_nb, int tpb_log2, int stot, int soff)
{
  __shared__ unsigned short As[2][4096];
  __shared__ unsigned short Bs[2][4096];
  const int t = threadIdx.x, w = t>>6, l = t&63;
  const int by = blockIdx.y;
  const int wsel = (by >= 2*sec_nb) ? 2 : (by >= sec_nb ? 1 : 0);
  const int Cl = (by - wsel*sec_nb)*128;            // col-block base within section
  const unsigned short* Wp = W + (long)wsel*sec_nb*128*K;
  const float* bias = (wsel==0) ? ba : (wsel==1 ? bb : bc);
  const int R = blockIdx.x*128, C = by*128;
  const long xbase = (long)(R>>tpb_log2)*stot + soff + (R & ((1<<tpb_log2)-1));
  const int wr = w>>1, wc = w&1;
  f32x4 acc[4][4] = {};
  const int nk = K>>5;

  auto stage = [&](int buf, int kt){
    const int k0 = kt*32;
    #pragma unroll
    for (int c=0;c<2;c++){
      int row = c*64 + (t>>2);
      int scol = ((t&3)<<3) ^ ((row&3)<<3);           // 4-way XOR pre-swizzle of source
      gll16(X + (xbase+row)*K + k0 + scol, &As[buf][c*2048 + w*512]);
      gll16(Wp + (long)(Cl+row)*K + k0 + scol, &Bs[buf][c*2048 + w*512]);
    }
  };

  stage(0,0);
  int buf = 0;
  for (int kt=0; kt<nk; kt++){
    __syncthreads();
    if (kt+1 < nk) stage(buf^1, kt+1);
    bf16x8 a[4], b[4];
    #pragma unroll
    for (int m=0;m<4;m++){
      int ar = wr*64 + m*16 + (l&15);
      int ac = ((l>>4)<<3) ^ ((ar&3)<<3);
      a[m] = *(const bf16x8*)&As[buf][ar*32 + ac];
      int br = wc*64 + m*16 + (l&15);
      int bc2 = ((l>>4)<<3) ^ ((br&3)<<3);
      b[m] = *(const bf16x8*)&Bs[buf][br*32 + bc2];
    }
    #pragma unroll
    for (int m=0;m<4;m++)
      #pragma unroll
      for (int n=0;n<4;n++)
        acc[m][n] = __builtin_amdgcn_mfma_f32_16x16x32_bf16(a[m], b[n], acc[m][n], 0,0,0);
    buf ^= 1;
  }

  #pragma unroll
  for (int m=0;m<4;m++){
    int row = R + wr*64 + m*16 + ((l>>4)<<2);
    #pragma unroll
    for (int n=0;n<4;n++){
      int cl = wc*64 + n*16 + (l&15);
      float bvv = bias[Cl + cl];
      int col = C + cl;
      #pragma unroll
      for (int r=0;r<4;r++){
        float v = acc[m][n][r] + bvv;
        long idx = (long)(row+r)*N + col;
        if (Yf) Yf[idx] = v;
        else Yb[idx] = f2bf(v);
      }
    }
  }
}

// ---------------- fused output GEMM (block-diagonal over rows) ----------------
// rows [0,2048): d_out_hs = AO[b][512+f] @ wo^T + bo ; rows [2048,3072): enc part.
__global__ __launch_bounds__(256) void k_gemmO(
    const unsigned short* __restrict__ X, const unsigned short* __restrict__ Wf,
    float* __restrict__ out, const float* __restrict__ bo, const float* __restrict__ bao)
{
  const int K = 3072;
  __shared__ unsigned short As[2][4096];
  __shared__ unsigned short Bs[2][4096];
  const int t = threadIdx.x, w = t>>6, l = t&63;
  const int bx = blockIdx.x, by = blockIdx.y;
  const bool enc = bx >= 16;
  const unsigned short* Wp = Wf + (enc ? 9437184 : 0);
  const float* bias = enc ? bao : bo;
  const int R = bx*128, C = by*128;
  long xbase, obase;
  if (!enc){ xbase = (long)(R>>10)*1536 + 512 + (R&1023); obase = (long)R*3072; }
  else { int Rp = R-2048; xbase = (long)(Rp>>9)*1536 + (Rp&511); obase = 6291456 + (long)Rp*3072; }
  const int wr = w>>1, wc = w&1;
  f32x4 acc[4][4] = {};

  auto stage = [&](int buf, int kt){
    const int k0 = kt*32;
    #pragma unroll
    for (int c=0;c<2;c++){
      int row = c*64 + (t>>2);
      int scol = ((t&3)<<3) ^ ((row&3)<<3);
      gll16(X + (xbase+row)*K + k0 + scol, &As[buf][c*2048 + w*512]);
      gll16(Wp + (long)(C+row)*K + k0 + scol, &Bs[buf][c*2048 + w*512]);
    }
  };

  stage(0,0);
  int buf = 0;
  for (int kt=0; kt<96; kt++){
    __syncthreads();
    if (kt+1 < 96) stage(buf^1, kt+1);
    bf16x8 a[4], b[4];
    #pragma unroll
    for (int m=0;m<4;m++){
      int ar = wr*64 + m*16 + (l&15);
      int ac = ((l>>4)<<3) ^ ((ar&3)<<3);
      a[m] = *(const bf16x8*)&As[buf][ar*32 + ac];
      int br = wc*64 + m*16 + (l&15);
      int bc2 = ((l>>4)<<3) ^ ((br&3)<<3);
      b[m] = *(const bf16x8*)&Bs[buf][br*32 + bc2];
    }
    #pragma unroll
    for (int m=0;m<4;m++)
      #pragma unroll
      for (int n=0;n<4;n++)
        acc[m][n] = __builtin_amdgcn_mfma_f32_16x16x32_bf16(a[m], b[n], acc[m][n], 0,0,0);
    buf ^= 1;
  }

  #pragma unroll
  for (int m=0;m<4;m++){
    int rl = wr*64 + m*16 + ((l>>4)<<2);
    #pragma unroll
    for (int n=0;n<4;n++){
      int col = C + wc*64 + n*16 + (l&15);
      float bvv = bias[col];
      #pragma unroll
      for (int r=0;r<4;r++)
        out[obase + (long)(rl+r)*3072 + col] = acc[m][n][r] + bvv;
    }
  }
}

// ---------------- fused RMSNorm + RoPE postprocess (one wave per (token,head)) ----------------
__global__ void k_ppqk(const unsigned short* __restrict__ Y, int ystr, int yoff,
    const float* __restrict__ nw,
    const float* __restrict__ cs, const float* __restrict__ sn, unsigned short* __restrict__ dst,
    int T_log2, int tpb_log2, int dest_off, int S, int no_batch,
    int pos_off, int pos_mask, float qscale)
{
  int rid = blockIdx.x*4 + (threadIdx.x>>6);
  int l = threadIdx.x & 63;
  int h = rid >> T_log2, tk = rid & ((1<<T_log2)-1);
  unsigned pair = *(const unsigned*)(Y + (long)tk*ystr + yoff + h*128 + 2*l);
  float x0 = bf2f((unsigned short)(pair&0xffff));
  float x1 = bf2f((unsigned short)(pair>>16));
  float ss = x0*x0 + x1*x1;
  #pragma unroll
  for (int m=1;m<64;m<<=1) ss += __shfl_xor(ss, m);
  float rr = rsqrtf(ss*(1.0f/128.0f) + 1e-6f);
  x0 *= rr*nw[2*l]; x1 *= rr*nw[2*l+1];
  int p = pos_off + (tk & pos_mask);
  float c0 = cs[p*128 + 2*l], c1 = cs[p*128 + 2*l+1];
  float s0 = sn[p*128 + 2*l], s1 = sn[p*128 + 2*l+1];
  float o0 = (x0*c0 - x1*s0)*qscale;
  float o1 = (x1*c1 + x0*s1)*qscale;
  long idx;
  if (no_batch) idx = (long)h*S + tk;
  else {
    int b = tk >> tpb_log2;
    int sq = dest_off + (tk & ((1<<tpb_log2)-1));
    idx = (long)(b*24+h)*S + sq;
  }
  unsigned out = (unsigned)f2bf(o0) | ((unsigned)f2bf(o1)<<16);
  *(unsigned*)(dst + idx*128 + 2*l) = out;
}

// ---------------- V reorder + transpose: Vt[(b,)h][d][j] ----------------
__global__ void k_ppv(const unsigned short* __restrict__ Y, int ystr, int yoff,
                      unsigned short* __restrict__ Vt, int vstr, int no_batch)
{
  __shared__ unsigned short tileS[64][136];
  int t = threadIdx.x, h = blockIdx.y;
  int tile0 = blockIdx.x*64;
  #pragma unroll
  for (int c=0;c<4;c++){
    int j = c*16 + (t>>4), col = (t&15)*8;
    *(u16x8*)&tileS[j][col] = *(const u16x8*)(Y + (long)(tile0+j)*ystr + yoff + h*128 + col);
  }
  __syncthreads();
  int d = t>>1, half = t&1;
  unsigned short tmp[32];
  #pragma unroll
  for (int i=0;i<32;i++) tmp[i] = tileS[half*32+i][d];
  long base;
  if (no_batch) base = ((long)h*128 + d)*vstr + tile0 + half*32;
  else { int b = tile0>>9; base = ((long)(b*24+h)*128 + d)*vstr + (tile0&511) + half*32; }
  #pragma unroll
  for (int k=0;k<4;k++) *(u16x8*)(Vt + base + k*8) = *(const u16x8*)&tmp[k*8];
}

// ---------------- flash attention: 64 Q-rows/block, KV tiles of 64 ----------------
// deferred-max (THR=8 in log2 domain) + per-lane partial row-sums (reduced once at end)
__global__ __launch_bounds__(256) void k_attn(
    const unsigned short* __restrict__ Q,
    const unsigned short* __restrict__ Ke, const unsigned short* __restrict__ Ki,
    const unsigned short* __restrict__ Ve, const unsigned short* __restrict__ Vi,
    unsigned short* __restrict__ AO)
{
  __shared__ unsigned short Ks[8192];          // [64 kv][128 d], XOR-swizzled
  __shared__ unsigned short Vs[8192];          // [128 d][64 kv], XOR-swizzled
  __shared__ unsigned short Ps[4][1408];       // per-wave P tile [16][88]
  const int t = threadIdx.x, w = t>>6, l = t&63;
  const int h = blockIdx.y, b = blockIdx.z;
  const int bh = b*24 + h;
  const int q0 = blockIdx.x*64 + w*16;

  bf16x8 qf[4];
  {
    const unsigned short* qp = Q + ((long)bh*1536 + q0 + (l&15))*128 + ((l>>4)<<3);
    #pragma unroll
    for (int kc=0;kc<4;kc++) qf[kc] = *(const bf16x8*)(qp + kc*32);
  }
  f32x4 o[8] = {};
  float mx[4] = {-1e30f,-1e30f,-1e30f,-1e30f};
  float ls[4] = {0,0,0,0};   // per-lane partial sums

  for (int jt=0; jt<40; jt++){
    const unsigned short *ksrc, *vsrc; int vstr;
    if (jt < 8){
      ksrc = Ke + ((long)bh*512 + jt*64)*128;
      vsrc = Ve + (long)bh*65536 + jt*64;
      vstr = 512;
    } else {
      ksrc = Ki + ((long)h*2048 + (jt-8)*64)*128;
      vsrc = Vi + (long)h*262144 + (jt-8)*64;
      vstr = 2048;
    }
    #pragma unroll
    for (int c=0;c<4;c++){
      int row = c*16 + (t>>4);
      int col = ((t&15)<<3) ^ ((row&7)<<3);
      gll16(ksrc + row*128 + col, &Ks[c*2048 + w*512]);
    }
    #pragma unroll
    for (int c=0;c<4;c++){
      int row = c*32 + (t>>3);
      int col = ((t&7)<<3) ^ ((row&7)<<3);
      gll16(vsrc + (long)row*vstr + col, &Vs[c*2048 + w*512]);
    }
    __syncthreads();

    f32x4 sf[4];
    __builtin_amdgcn_s_setprio(1);
    #pragma unroll
    for (int ct=0;ct<4;ct++){
      f32x4 s = {};
      #pragma unroll
      for (int kc=0;kc<4;kc++){
        int krow = ct*16 + (l&15);
        int kcol = (kc*32 + ((l>>4)<<3)) ^ ((krow&7)<<3);
        bf16x8 kb = *(const bf16x8*)&Ks[krow*128 + kcol];
        s = __builtin_amdgcn_mfma_f32_16x16x32_bf16(qf[kc], kb, s, 0,0,0);
      }
      sf[ct] = s;
    }
    __builtin_amdgcn_s_setprio(0);

    // per-lane tile max; rescale only if some row's max grew past mx+8
    float pm[4]; int ok = 1;
    #pragma unroll
    for (int r=0;r<4;r++){
      pm[r] = fmaxf(fmaxf(sf[0][r],sf[1][r]), fmaxf(sf[2][r],sf[3][r]));
      ok &= (pm[r] <= mx[r] + 8.0f);
    }
    if (!__all(ok)){
      #pragma unroll
      for (int r=0;r<4;r++){
        float tmax = pm[r];
        #pragma unroll
        for (int m=1;m<16;m<<=1) tmax = fmaxf(tmax, __shfl_xor(tmax, m));
        float mn = fmaxf(mx[r], tmax);
        float al = exp2f(mx[r]-mn);
        mx[r] = mn;
        ls[r] *= al;
        #pragma unroll
        for (int f=0;f<8;f++) o[f][r] *= al;
      }
    }
    #pragma unroll
    for (int ct=0;ct<4;ct++){
      #pragma unroll
      for (int r=0;r<4;r++){
        float pv = exp2f(sf[ct][r]-mx[r]);
        ls[r] += pv;
        int prow = ((l>>4)<<2) + r;
        Ps[w][prow*88 + ct*16 + (l&15)] = f2bf(pv);
      }
    }
    bf16x8 pa[2];
    #pragma unroll
    for (int kc=0;kc<2;kc++)
      pa[kc] = *(const bf16x8*)&Ps[w][(l&15)*88 + kc*32 + ((l>>4)<<3)];
    __builtin_amdgcn_s_setprio(1);
    #pragma unroll
    for (int f=0;f<8;f++){
      #pragma unroll
      for (int kc=0;kc<2;kc++){
        int vrow = f*16 + (l&15);
        int vcol = (kc*32 + ((l>>4)<<3)) ^ ((vrow&7)<<3);
        bf16x8 vb = *(const bf16x8*)&Vs[vrow*64 + vcol];
        o[f] = __builtin_amdgcn_mfma_f32_16x16x32_bf16(pa[kc], vb, o[f], 0,0,0);
      }
    }
    __builtin_amdgcn_s_setprio(0);
    __syncthreads();
  }

  #pragma unroll
  for (int r=0;r<4;r++){
    #pragma unroll
    for (int m=1;m<16;m<<=1) ls[r] += __shfl_xor(ls[r], m);
  }
  #pragma unroll
  for (int r=0;r<4;r++){
    int qrow = q0 + ((l>>4)<<2) + r;
    float inv = 1.0f/ls[r];
    #pragma unroll
    for (int f=0;f<8;f++){
      AO[((long)b*1536 + qrow)*3072 + h*128 + f*16 + (l&15)] = f2bf(o[f][r]*inv);
    }
  }
}

// ---------------- host launch ----------------
extern "C" void kernel_launch(void* const* d_in, const int* in_sizes, int n_in,
                              void* d_out, int out_size, void* d_ws, size_t ws_size,
                              hipStream_t stream)
{
  const float* hs  = (const float*)d_in[0];
  const float* ehs = (const float*)d_in[1];
  const float* rc  = (const float*)d_in[2];
  const float* rs_ = (const float*)d_in[3];
  const float* wq = (const float*)d_in[4];  const float* bq = (const float*)d_in[5];
  const float* wk = (const float*)d_in[6];  const float* bk = (const float*)d_in[7];
  const float* wv = (const float*)d_in[8];  const float* bv = (const float*)d_in[9];
  const float* waq= (const float*)d_in[10]; const float* baq= (const float*)d_in[11];
  const float* wak= (const float*)d_in[12]; const float* bak= (const float*)d_in[13];
  const float* wav= (const float*)d_in[14]; const float* bav= (const float*)d_in[15];
  const float* wo = (const float*)d_in[16]; const float* bo = (const float*)d_in[17];
  const float* wao= (const float*)d_in[18]; const float* bao= (const float*)d_in[19];
  const float* nq = (const float*)d_in[20]; const float* nk = (const float*)d_in[21];
  const float* naq= (const float*)d_in[22]; const float* nak= (const float*)d_in[23];

  const float qsc = (float)(0.08838834764831845 * 1.4426950408889634); // scale * log2(e)

  char* p = (char*)d_ws;
  auto alloc = [&](size_t bytes){ char* r = p; p += bytes; return r; };

  if (ws_size >= (size_t)169869312){
    // ---------- fused path (170 MB) ----------
    unsigned short* Xh = (unsigned short*)alloc(12582912);  // hidden bf16 [2048][3072]
    unsigned short* Xe = (unsigned short*)alloc(6291456);   // encoder bf16 [1024][3072]
    unsigned short* Wb = (unsigned short*)alloc(56623104);  // fused weights bf16 [9216][3072]
    unsigned short* Yb = (unsigned short*)alloc(37748736);  // fused proj out bf16 [2048][9216]
    unsigned short* Qb = (unsigned short*)alloc(18874368);  // Q [2][24][1536][128]
    unsigned short* Ke = (unsigned short*)alloc(6291456);   // Kenc [2][24][512][128]
    unsigned short* Ki = (unsigned short*)alloc(12582912);  // Kimg [24][2048][128]
    unsigned short* Ve = (unsigned short*)alloc(6291456);   // Vtenc [2][24][128][512]
    unsigned short* Vi = (unsigned short*)alloc(12582912);  // Vtimg [24][128][2048]
    unsigned short* AO = Xh;                                // aliases Xh+Xe (dead by attn)

    k_cast<<<6144,256,0,stream>>>(hs, Xh, 1572864);
    k_cast<<<3072,256,0,stream>>>(ehs, Xe, 786432);

    // image fused QKV
    k_cast<<<9216,256,0,stream>>>(wq, Wb, 2359296);
    k_cast<<<9216,256,0,stream>>>(wk, Wb + 9437184, 2359296);
    k_cast<<<9216,256,0,stream>>>(wv, Wb + 18874368, 2359296);
    k_gemm<<<dim3(16,72),256,0,stream>>>(Xh, Wb, Yb, nullptr, bq, bk, bv, 9216,3072, 24, 20,0,0);
    k_ppqk<<<12288,256,0,stream>>>(Yb, 9216, 0,    nq, rc, rs_, Qb, 11, 10, 512, 1536, 0, 512, 1023, qsc);
    k_ppqk<<<12288,256,0,stream>>>(Yb, 9216, 3072, nk, rc, rs_, Ki, 11, 0,  0,   2048, 1, 512, 1023, 1.0f);
    k_ppv<<<dim3(32,24),256,0,stream>>>(Yb, 9216, 6144, Vi, 2048, 1);

    // encoder fused QKV (reuses Wb, Yb)
    k_cast<<<9216,256,0,stream>>>(waq, Wb, 2359296);
    k_cast<<<9216,256,0,stream>>>(wak, Wb + 9437184, 2359296);
    k_cast<<<9216,256,0,stream>>>(wav, Wb + 18874368, 2359296);
    k_gemm<<<dim3(8,72),256,0,stream>>>(Xe, Wb, Yb, nullptr, baq, bak, bav, 9216,3072, 24, 20,0,0);
    k_ppqk<<<6144,256,0,stream>>>(Yb, 9216, 0,    naq, rc, rs_, Qb, 10, 9, 0, 1536, 0, 0, 511, qsc);
    k_ppqk<<<6144,256,0,stream>>>(Yb, 9216, 3072, nak, rc, rs_, Ke, 10, 9, 0, 512,  0, 0, 511, 1.0f);
    k_ppv<<<dim3(16,24),256,0,stream>>>(Yb, 9216, 6144, Ve, 512, 0);

    // attention
    k_attn<<<dim3(24,24,2),256,0,stream>>>(Qb, Ke, Ki, Ve, Vi, AO);

    // fused output projections (block-diagonal rows)
    k_cast<<<9216,256,0,stream>>>(wo,  Wb, 2359296);
    k_cast<<<9216,256,0,stream>>>(wao, Wb + 9437184, 2359296);
    k_gemmO<<<dim3(24,24),256,0,stream>>>(AO, Wb, (float*)d_out, bo, bao);
  } else {
    // ---------- fallback path (107 MB, round-1 structure) ----------
    unsigned short* Xh = (unsigned short*)alloc(12582912);
    unsigned short* Xe = (unsigned short*)alloc(6291456);
    unsigned short* Wb = (unsigned short*)alloc(18874368);
    unsigned short* Yb = (unsigned short*)alloc(12582912);
    unsigned short* Qb = (unsigned short*)alloc(18874368);
    unsigned short* Ke = (unsigned short*)alloc(6291456);
    unsigned short* Ki = (unsigned short*)alloc(12582912);
    unsigned short* Ve = (unsigned short*)alloc(6291456);
    unsigned short* Vi = (unsigned short*)alloc(12582912);
    unsigned short* AO = Xh;

    k_cast<<<6144,256,0,stream>>>(hs, Xh, 1572864);
    k_cast<<<3072,256,0,stream>>>(ehs, Xe, 786432);
    auto cW = [&](const float* ww){ k_cast<<<9216,256,0,stream>>>(ww, Wb, 2359296); };

    cW(wq);
    k_gemm<<<dim3(16,24),256,0,stream>>>(Xh, Wb, Yb, nullptr, bq,bq,bq, 3072,3072, 24, 20,0,0);
    k_ppqk<<<12288,256,0,stream>>>(Yb, 3072, 0, nq, rc, rs_, Qb, 11, 10, 512, 1536, 0, 512, 1023, qsc);
    cW(wk);
    k_gemm<<<dim3(16,24),256,0,stream>>>(Xh, Wb, Yb, nullptr, bk,bk,bk, 3072,3072, 24, 20,0,0);
    k_ppqk<<<12288,256,0,stream>>>(Yb, 3072, 0, nk, rc, rs_, Ki, 11, 0, 0, 2048, 1, 512, 1023, 1.0f);
    cW(wv);
    k_gemm<<<dim3(16,24),256,0,stream>>>(Xh, Wb, Yb, nullptr, bv,bv,bv, 3072,3072, 24, 20,0,0);
    k_ppv<<<dim3(32,24),256,0,stream>>>(Yb, 3072, 0, Vi, 2048, 1);

    cW(waq);
    k_gemm<<<dim3(8,24),256,0,stream>>>(Xe, Wb, Yb, nullptr, baq,baq,baq, 3072,3072, 24, 20,0,0);
    k_ppqk<<<6144,256,0,stream>>>(Yb, 3072, 0, naq, rc, rs_, Qb, 10, 9, 0, 1536, 0, 0, 511, qsc);
    cW(wak);
    k_gemm<<<dim3(8,24),256,0,stream>>>(Xe, Wb, Yb, nullptr, bak,bak,bak, 3072,3072, 24, 20,0,0);
    k_ppqk<<<6144,256,0,stream>>>(Yb, 3072, 0, nak, rc, rs_, Ke, 10, 9, 0, 512, 0, 0, 511, 1.0f);
    cW(wav);
    k_gemm<<<dim3(8,24),256,0,stream>>>(Xe, Wb, Yb, nullptr, bav,bav,bav, 3072,3072, 24, 20,0,0);
    k_ppv<<<dim3(16,24),256,0,stream>>>(Yb, 3072, 0, Ve, 512, 0);

    k_attn<<<dim3(24,24,2),256,0,stream>>>(Qb, Ke, Ki, Ve, Vi, AO);

    cW(wo);
    k_gemm<<<dim3(16,24),256,0,stream>>>(AO, Wb, nullptr, (float*)d_out, bo,bo,bo, 3072,3072, 24, 10, 1536, 512);
    cW(wao);
    k_gemm<<<dim3(8,24),256,0,stream>>>(AO, Wb, nullptr, (float*)d_out + 6291456, bao,bao,bao, 3072,3072, 24, 9, 1536, 0);
  }
}